// Round 13
// baseline (2304.786 us; speedup 1.0000x reference)
//
#include <hip/hip_runtime.h>
#include <stdint.h>

#define NB 256          // batch
#define NH 1024         // hidden
#define NPOSE 135
#define NPPAD 160       // pose padded to 160
#define NSTEPS 143      // 119 encoder + 24 decoder cell steps
#define NDEC 24
#define KTOT 1184       // 1024 (h) + 160 (x padded)
#define LSTR 168        // LDS row stride for x-B chunk
#define NWG 256

typedef __bf16 bf16;
typedef __attribute__((ext_vector_type(8))) __bf16 bf16x8;
typedef __attribute__((ext_vector_type(4))) float f32x4;
typedef __attribute__((ext_vector_type(16))) float f32x16;
typedef __attribute__((ext_vector_type(4))) uint32_t u32x4;

// ---- ws layout (bytes) ----
#define WCAT_OFF 0
#define WCAT_BYTES (4096l * KTOT * 2)
#define WFC_OFF  (WCAT_OFF + WCAT_BYTES)
#define WFC_BYTES (144l * 1024 * 2)
#define X_OFF    (WFC_OFF + WFC_BYTES)
#define X_BYTES  (143l * NB * NPPAD * 2)
#define H_OFF    (X_OFF + X_BYTES)
#define H_BYTES2    (2l * NB * NH * 2)     // fallback: ping-pong
#define H_BYTES144  (144l * NB * NH * 2)   // deep: slot per step -> cacheable
#define BAR_BYTES 16384
// bar ints, one counter per 128B line:
//   cnt[bb][ch] at bar[(bb*8+ch)*32]  (h-chunk ready; 8 producers, +8/step)
//   xcnt[bb]    at bar[(32+bb)*32]    (decoder X ready; +4/out-step)

__device__ __forceinline__ u32x4 llc_ld16(const void* p) {
  u32x4 v;
  asm volatile("global_load_dwordx4 %0, %1, off sc0 sc1"
               : "=v"(v) : "v"(p) : "memory");
  return v;
}
__device__ __forceinline__ u32x4 g_ld16(const void* p) {   // cached
  u32x4 v;
  asm volatile("global_load_dwordx4 %0, %1, off"
               : "=v"(v) : "v"(p) : "memory");
  return v;
}
__device__ __forceinline__ u32x4 ld16sel(const void* p, bool cached) {
  return cached ? g_ld16(p) : llc_ld16(p);
}
// stores: sc1 (agent scope, reach LLC past own-XCD L2). sc0 dropped — it is
// system-scope and (r12 WRITE_SIZE evidence) forced write-through to HBM.
__device__ __forceinline__ void llc_st2(void* p, uint32_t v) {
  asm volatile("global_store_short %0, %1, off sc1"
               :: "v"(p), "v"(v) : "memory");
}
#define WAIT_VM(n) do { \
    asm volatile("s_waitcnt vmcnt(" #n ")" ::: "memory"); \
    __builtin_amdgcn_sched_barrier(0); } while (0)

// NOTE (r5/r11): polls force vmcnt(0) — allowed ONLY at step tail / decoder.
#define POLL(ptr, tgt) do { \
    while (__hip_atomic_load((ptr), __ATOMIC_RELAXED, __HIP_MEMORY_SCOPE_AGENT) < (tgt)) \
      __builtin_amdgcn_s_sleep(1); \
  } while (0)
#define POLL_ALL8(tgt) do { \
    for (;;) { \
      int v_ = __hip_atomic_load(&bar[(bb * 8 + (lane & 7)) * 32], \
                                 __ATOMIC_RELAXED, __HIP_MEMORY_SCOPE_AGENT); \
      if (__all(v_ >= (tgt))) break; \
      __builtin_amdgcn_s_sleep(1); \
    } } while (0)

__global__ void k_zero(uint32_t* p, int n) {
  int i = blockIdx.x * blockDim.x + threadIdx.x;
  int st = gridDim.x * blockDim.x;
  for (; i < n; i += st) p[i] = 0u;
}

__global__ void k_wcat(const float* __restrict__ Whh, const float* __restrict__ Wih,
                       bf16* __restrict__ W) {
  int n = blockIdx.x;
  for (int kk = threadIdx.x; kk < KTOT; kk += blockDim.x) {
    float v = 0.f;
    if (kk < NH) v = Whh[(size_t)n * NH + kk];
    else if (kk - NH < NPOSE) v = Wih[(size_t)n * NPOSE + (kk - NH)];
    W[(size_t)n * KTOT + kk] = (bf16)v;
  }
}

__global__ void k_wfc(const float* __restrict__ Wfc, bf16* __restrict__ W) {
  int p = blockIdx.x;
  for (int kk = threadIdx.x; kk < NH; kk += blockDim.x) {
    float v = (p < NPOSE) ? Wfc[(size_t)p * NH + kk] : 0.f;
    W[(size_t)p * NH + kk] = (bf16)v;
  }
}

__global__ void k_x(const float* __restrict__ poses, bf16* __restrict__ X) {
  int idx = blockIdx.x;          // t*256 + b, t in [0,120)
  int t = idx >> 8, b = idx & 255;
  int p = threadIdx.x;
  if (p < NPPAD) {
    float v = (p < NPOSE) ? poses[((size_t)b * 144 + t) * NPOSE + p] : 0.f;
    X[(size_t)idx * NPPAD + p] = (bf16)v;
  }
}

__device__ __forceinline__ float sigm(float x) { return 1.f / (1.f + __expf(-x)); }
__device__ __forceinline__ float tanh_(float x) {
  float e = __expf(2.f * x);
  return 1.f - 2.f / (e + 1.f);
}

template <bool DEEP>
__global__ __launch_bounds__(256, 1) void
k_main(const float* __restrict__ poses, const float* __restrict__ bfc,
       const bf16* __restrict__ Wcat, const bf16* __restrict__ Wfcb,
       bf16* __restrict__ X, bf16* __restrict__ H, int* __restrict__ bar,
       float* __restrict__ out) {
  // W staged to LDS once (r7/r9 layout + swizzle key r&15).
  // 32x32 MFMA, 4 waves = 2 batch-tiles x 2 gate-col-tiles:
  // per-CU LDS B-reads HALVE vs r9 (each B-frag read by 2 waves, not 4).
  __shared__ bf16 BldsH[8 * 64 * 128];     // 131072 B
  __shared__ bf16 BldsX[64 * LSTR];        // 21504 B
  __shared__ float XCH[2 * 64 * 18];       // 9216 B: (g,o)->(i,f) wave exchange

  const int tid  = threadIdx.x;
  const int lane = tid & 63;
  const int wv   = tid >> 6;
  const int lrow = lane & 31;              // 32x32 row/col index
  const int half = lane >> 5;              // k-half
  const int l15  = lane & 15;
  const int cl   = lane & 15;              // decoder 16x16 indices
  const int quad = lane >> 4;
  const int bt   = wv & 1;                 // batch tile (32 rows)
  const int ct   = wv >> 1;                // col tile: 0 -> gates{0,1}, 1 -> {2,3}
  const int ct32 = ct * 32;
  const int L    = blockIdx.x;
  const int jb = (L & 7) * 8 + ((L >> 3) & 7);   // r9 XCD-spread mapping
  const int bb = L >> 6;
  const int b0 = bb * 64;
  const int j0 = jb * 16;
  const int mych = jb >> 3;
  const bool is_out = ((L & 7) == 7) && (((L >> 3) & 7) < 4);
  const int brow0 = bb * 64 + ((L >> 3) & 7) * 16;

  // ---- one-time B staging (plain loads; compiler-managed waits) ----
  for (int t = tid; t < 8 * 64 * 16; t += 256) {
    int c = t >> 10, rem = t & 1023, r = rem >> 4, xb = rem & 15;
    u32x4 v = *(const u32x4*)&Wcat[(size_t)((r >> 4) * NH + j0 + (r & 15)) * KTOT
                                   + c * 128 + xb * 8];
    *(u32x4*)&BldsH[(c * 64 + r) * 128 + ((xb ^ (r & 15)) << 3)] = v;
  }
  for (int it = 0; it < 5; ++it) {
    int u = tid + it * 256, r = u / 20, iu = u % 20;
    u32x4 v = *(const u32x4*)&Wcat[(size_t)((r >> 4) * NH + j0 + (r & 15)) * KTOT
                                   + 1024 + iu * 8];
    *(u32x4*)&BldsX[r * LSTR + iu * 8] = v;
  }
  __syncthreads();

  // ---- per-lane A addressing (direct-to-fragment, r8-verified 32x32 layout) ----
  const int arow = b0 + 32 * bt + lrow;               // batch row this lane owns
  const size_t aBase  = (size_t)arow * NH + half * 8; // + chn*128 + kk*16
  const size_t axBase = (size_t)arow * NPPAD + half * 8;

  u32x4 A0[8], A1[8], A2[8], AX[10];
  f32x16 acc;
  float cst[8];
  #pragma unroll
  for (int r = 0; r < 8; ++r) cst[r] = 0.f;

#define ISSUE_AH(SET, HP, chn) do { \
    const bf16* ga_ = (HP) + aBase + (chn) * 128; \
    _Pragma("unroll") \
    for (int kk_ = 0; kk_ < 8; ++kk_) SET[kk_] = ld16sel(ga_ + kk_ * 16, DEEP); } while (0)
#define ISSUE_AX(sv) do { \
    const bf16* ga_ = X + (size_t)(sv) * NB * NPPAD + axBase; \
    if ((sv) < 120) { \
      _Pragma("unroll") \
      for (int kk_ = 0; kk_ < 10; ++kk_) AX[kk_] = g_ld16(ga_ + kk_ * 16); \
    } else { \
      _Pragma("unroll") \
      for (int kk_ = 0; kk_ < 10; ++kk_) AX[kk_] = ld16sel(ga_ + kk_ * 16, DEEP); \
    } } while (0)
#define MFMA_H32(SET, c) do { \
    _Pragma("unroll") \
    for (int kk_ = 0; kk_ < 8; ++kk_) { \
      bf16x8 af_ = __builtin_bit_cast(bf16x8, SET[kk_]); \
      bf16x8 bw_ = *(const bf16x8*)&BldsH[((c) * 64 + ct32 + lrow) * 128 \
                                          + (((kk_ * 2 + half) ^ l15) << 3)]; \
      acc = __builtin_amdgcn_mfma_f32_32x32x16_bf16(af_, bw_, acc, 0, 0, 0); \
    } } while (0)
#define MFMA_X32() do { \
    _Pragma("unroll") \
    for (int kk_ = 0; kk_ < 10; ++kk_) { \
      bf16x8 af_ = __builtin_bit_cast(bf16x8, AX[kk_]); \
      bf16x8 bw_ = *(const bf16x8*)&BldsX[(ct32 + lrow) * LSTR + kk_ * 16 + half * 8]; \
      acc = __builtin_amdgcn_mfma_f32_32x32x16_bf16(af_, bw_, acc, 0, 0, 0); \
    } } while (0)

  // ---- prologue: A-chunks 0,1 of step 0 (h(0)=zeros, slot 0) ----
  ISSUE_AH(A0, H, 0);
  ISSUE_AH(A1, H, 1);

  for (int s = 0; s < NSTEPS; ++s) {
    const bf16* Hr = H + (size_t)(DEEP ? s : (s & 1)) * (NB * NH);
    bf16* Hw = H + (size_t)(DEEP ? (s + 1) : ((s + 1) & 1)) * (NB * NH);
    acc = (f32x16)(0.f);

    // steady-state: depth-2, 8-load sets; ledger: 16 out after prologue,
    // issue 8 -> 24, wait(16) retires the consumed set. Mirrors r9 x2.
    ISSUE_AH(A2, Hr, 2); WAIT_VM(16); MFMA_H32(A0, 0);
    ISSUE_AH(A0, Hr, 3); WAIT_VM(16); MFMA_H32(A1, 1);
    ISSUE_AH(A1, Hr, 4); WAIT_VM(16); MFMA_H32(A2, 2);
    ISSUE_AH(A2, Hr, 5); WAIT_VM(16); MFMA_H32(A0, 3);
    ISSUE_AH(A0, Hr, 6); WAIT_VM(16); MFMA_H32(A1, 4);
    ISSUE_AH(A1, Hr, 7); WAIT_VM(16); MFMA_H32(A2, 5);
    if (s >= 120) POLL(&bar[(32 + bb) * 32], 4 * (s - 119));
    ISSUE_AX(s);         WAIT_VM(18); MFMA_H32(A0, 6);
                         WAIT_VM(10); MFMA_H32(A1, 7);
                         WAIT_VM(0);  MFMA_X32();

    // ---- in-wave merge (r8-verified): pairs l, l^16 ----
    float va[8], vb[8];           // ct0: (i,f);  ct1: (g,o)
    #pragma unroll
    for (int r8i = 0; r8i < 8; ++r8i) {
      float sa = __shfl_xor(acc[r8i], 16);
      float sb = __shfl_xor(acc[r8i + 8], 16);
      const bool lo = (lrow < 16);
      va[r8i] = lo ? acc[r8i] : sb;        // gate 2ct+0
      vb[r8i] = lo ? sa : acc[r8i + 8];    // gate 2ct+1
    }
    const int xbase = (bt * 64 + lane) * 18;
    if (ct == 1) {                // publish tanh(g), sigm(o)
      #pragma unroll
      for (int r8i = 0; r8i < 8; ++r8i) {
        XCH[xbase + r8i * 2]     = tanh_(va[r8i]);
        XCH[xbase + r8i * 2 + 1] = sigm(vb[r8i]);
      }
    }
    __syncthreads();              // (g,o) products visible

    if (ct == 0) {                // activation + h-store (sc1 write) on ct0 waves
      #pragma unroll
      for (int r8i = 0; r8i < 8; ++r8i) {
        float tg = XCH[xbase + r8i * 2];
        float so = XCH[xbase + r8i * 2 + 1];
        float cn = sigm(vb[r8i]) * cst[r8i] + sigm(va[r8i]) * tg;
        cst[r8i] = cn;
        float h = so * tanh_(cn);
        int reg = (lrow < 16) ? r8i : (r8i + 8);
        int row32 = (reg & 3) + 8 * (reg >> 2) + 4 * half;
        bf16 hb = (bf16)h;
        llc_st2(&Hw[(size_t)(b0 + 32 * bt + row32) * NH + j0 + l15],
                (uint32_t)__builtin_bit_cast(uint16_t, hb));
      }
      WAIT_VM(0);                 // h acked at LLC
    }
    __syncthreads();              // both ct0 waves drained
    if (tid == 0) atomicAdd(&bar[(bb * 8 + mych) * 32], 1);

    if (s >= 119 && is_out) {   // decoder: out = inp + h_new @ W_fc^T + b_fc (r9 verbatim)
      const int k = s - 119;
      POLL_ALL8(8 * (s + 1));
      f32x4 oa[3] = {{0,0,0,0},{0,0,0,0},{0,0,0,0}};
      const bf16* hrow = Hw + (size_t)(brow0 + cl) * NH;
      for (int kb = 0; kb < 4; ++kb) {
        u32x4 hv[8];
        #pragma unroll
        for (int t = 0; t < 8; ++t)
          hv[t] = ld16sel(&hrow[(kb * 8 + t) * 32 + quad * 8], DEEP);
        WAIT_VM(0);
        #pragma unroll
        for (int t = 0; t < 8; ++t) {
          bf16x8 af = __builtin_bit_cast(bf16x8, hv[t]);
          #pragma unroll
          for (int i = 0; i < 3; ++i) {
            int ctd = wv + i * 4;
            if (ctd > 8) continue;
            bf16x8 bw = *(const bf16x8*)&Wfcb[(size_t)(ctd * 16 + cl) * NH
                                              + (kb * 8 + t) * 32 + quad * 8];
            oa[i] = __builtin_amdgcn_mfma_f32_16x16x32_bf16(af, bw, oa[i], 0, 0, 0);
          }
        }
      }
      #pragma unroll
      for (int i = 0; i < 3; ++i) {
        int ctd = wv + i * 4;
        if (ctd > 8) continue;
        int p = ctd * 16 + cl;
        if (p < NPOSE) {
          #pragma unroll
          for (int r = 0; r < 4; ++r) {
            int b = brow0 + quad * 4 + r;
            float inp = (k == 0) ? poses[((size_t)b * 144 + 119) * NPOSE + p]
                                 : out[((size_t)b * NDEC + (k - 1)) * NPOSE + p];
            float v = oa[i][r] + inp + bfc[p];       // additive chain kept fp32
            out[((size_t)b * NDEC + k) * NPOSE + p] = v;
            if (s + 1 < NSTEPS) {
              bf16 xb = (bf16)v;
              llc_st2(&X[((size_t)(s + 1) * NB + b) * NPPAD + p],
                      (uint32_t)__builtin_bit_cast(uint16_t, xb));
            }
          }
        }
      }
      if (s + 1 < NSTEPS) {
        WAIT_VM(0);
        __syncthreads();
        if (tid == 0) atomicAdd(&bar[(32 + bb) * 32], 1);
      }
    }

    // ---- tail: ballot readiness poll, then prefetch step s+1 chunks 0,1 ----
    if (s + 1 < NSTEPS) {
      POLL_ALL8(8 * (s + 1));
      ISSUE_AH(A0, Hw, 0);
      ISSUE_AH(A1, Hw, 1);
    }
  }
}

extern "C" void kernel_launch(void* const* d_in, const int* in_sizes, int n_in,
                              void* d_out, int out_size, void* d_ws, size_t ws_size,
                              hipStream_t stream) {
  const float* poses = (const float*)d_in[0];
  const float* Wih   = (const float*)d_in[1];
  const float* Whh   = (const float*)d_in[2];
  const float* Wfc   = (const float*)d_in[3];
  const float* bfc   = (const float*)d_in[4];

  const size_t need_deep = (size_t)H_OFF + H_BYTES144 + BAR_BYTES;
  const size_t need_min  = (size_t)H_OFF + H_BYTES2 + BAR_BYTES;
  if (ws_size < need_min) return;
  const bool deep = ws_size >= need_deep;
  const size_t hbytes = deep ? (size_t)H_BYTES144 : (size_t)H_BYTES2;

  char* ws = (char*)d_ws;
  bf16* Wcat = (bf16*)(ws + WCAT_OFF);
  bf16* Wfcb = (bf16*)(ws + WFC_OFF);
  bf16* X    = (bf16*)(ws + X_OFF);
  bf16* H    = (bf16*)(ws + H_OFF);
  int*  bar  = (int*)(ws + H_OFF + hbytes);

  if (deep) {
    k_zero<<<256, 256, 0, stream>>>((uint32_t*)(ws + H_OFF), (int)(NB * NH * 2 / 4));
    k_zero<<<32, 256, 0, stream>>>((uint32_t*)bar, BAR_BYTES / 4);
  } else {
    k_zero<<<256, 256, 0, stream>>>((uint32_t*)(ws + H_OFF),
                                    (int)((H_BYTES2 + BAR_BYTES) / 4));
  }
  k_zero<<<256, 256, 0, stream>>>((uint32_t*)(X + (size_t)120 * NB * NPPAD),
                                  (int)(23l * NB * NPPAD * 2 / 4));
  k_wcat<<<4096, 256, 0, stream>>>(Whh, Wih, Wcat);
  k_wfc<<<144, 256, 0, stream>>>(Wfc, Wfcb);
  k_x<<<120 * 256, 256, 0, stream>>>(poses, X);
  if (deep)
    k_main<true><<<NWG, 256, 0, stream>>>(poses, bfc, Wcat, Wfcb, X, H, bar,
                                          (float*)d_out);
  else
    k_main<false><<<NWG, 256, 0, stream>>>(poses, bfc, Wcat, Wfcb, X, H, bar,
                                           (float*)d_out);
}

// Round 14
// 1668.653 us; speedup vs baseline: 1.3812x; 1.3812x over previous
//
#include <hip/hip_runtime.h>
#include <stdint.h>

#define NB 256          // batch
#define NH 1024         // hidden
#define NPOSE 135
#define NPPAD 160       // pose padded to 160
#define NSTEPS 143      // 119 encoder + 24 decoder cell steps
#define NDEC 24
#define KTOT 1184       // 1024 (h) + 160 (x padded)
#define LSTR 168        // LDS row stride for x-B chunk
#define NWG 256

typedef __bf16 bf16;
typedef __attribute__((ext_vector_type(8))) __bf16 bf16x8;
typedef __attribute__((ext_vector_type(4))) float f32x4;
typedef __attribute__((ext_vector_type(4))) uint32_t u32x4;

// ---- ws layout (bytes) ----
#define WCAT_OFF 0
#define WCAT_BYTES (4096l * KTOT * 2)
#define WFC_OFF  (WCAT_OFF + WCAT_BYTES)
#define WFC_BYTES (144l * 1024 * 2)
#define X_OFF    (WFC_OFF + WFC_BYTES)
#define X_BYTES  (143l * NB * NPPAD * 2)
#define H_OFF    (X_OFF + X_BYTES)
#define H_BYTES2    (2l * NB * NH * 2)     // fallback: ping-pong
#define H_BYTES144  (144l * NB * NH * 2)   // deep: slot per step -> cacheable
#define BAR_BYTES 16384
// bar ints, one counter per 128B line:
//   cnt[bb][ch] at bar[(bb*8+ch)*32]  (h-128chunk ready; 8 producers, +8/step)
//   xcnt[bb]    at bar[(32+bb)*32]    (decoder X ready; +4/out-step)

__device__ __forceinline__ u32x4 llc_ld16(const void* p) {
  u32x4 v;
  asm volatile("global_load_dwordx4 %0, %1, off sc0 sc1"
               : "=v"(v) : "v"(p) : "memory");
  return v;
}
__device__ __forceinline__ u32x4 g_ld16(const void* p) {   // cached
  u32x4 v;
  asm volatile("global_load_dwordx4 %0, %1, off"
               : "=v"(v) : "v"(p) : "memory");
  return v;
}
__device__ __forceinline__ u32x4 ld16sel(const void* p, bool cached) {
  return cached ? g_ld16(p) : llc_ld16(p);
}
__device__ __forceinline__ void llc_st2(void* p, uint32_t v) {
  asm volatile("global_store_short %0, %1, off sc0 sc1"
               :: "v"(p), "v"(v) : "memory");
}
#define WAIT_VM(n) do { \
    asm volatile("s_waitcnt vmcnt(" #n ")" ::: "memory"); \
    __builtin_amdgcn_sched_barrier(0); } while (0)

// NOTE (r5/r11): polls force vmcnt(0) — allowed ONLY at step tail / decoder
// boundary (the xcnt poll's drain is a true dependency wait anyway).
#define POLL(ptr, tgt) do { \
    while (__hip_atomic_load((ptr), __ATOMIC_RELAXED, __HIP_MEMORY_SCOPE_AGENT) < (tgt)) \
      __builtin_amdgcn_s_sleep(1); \
  } while (0)
#define POLL_ALL8(tgt) do { \
    for (;;) { \
      int v_ = __hip_atomic_load(&bar[(bb * 8 + (lane & 7)) * 32], \
                                 __ATOMIC_RELAXED, __HIP_MEMORY_SCOPE_AGENT); \
      if (__all(v_ >= (tgt))) break; \
      __builtin_amdgcn_s_sleep(1); \
    } } while (0)

__global__ void k_zero(uint32_t* p, int n) {
  int i = blockIdx.x * blockDim.x + threadIdx.x;
  int st = gridDim.x * blockDim.x;
  for (; i < n; i += st) p[i] = 0u;
}

__global__ void k_wcat(const float* __restrict__ Whh, const float* __restrict__ Wih,
                       bf16* __restrict__ W) {
  int n = blockIdx.x;
  for (int kk = threadIdx.x; kk < KTOT; kk += blockDim.x) {
    float v = 0.f;
    if (kk < NH) v = Whh[(size_t)n * NH + kk];
    else if (kk - NH < NPOSE) v = Wih[(size_t)n * NPOSE + (kk - NH)];
    W[(size_t)n * KTOT + kk] = (bf16)v;
  }
}

__global__ void k_wfc(const float* __restrict__ Wfc, bf16* __restrict__ W) {
  int p = blockIdx.x;
  for (int kk = threadIdx.x; kk < NH; kk += blockDim.x) {
    float v = (p < NPOSE) ? Wfc[(size_t)p * NH + kk] : 0.f;
    W[(size_t)p * NH + kk] = (bf16)v;
  }
}

__global__ void k_x(const float* __restrict__ poses, bf16* __restrict__ X) {
  int idx = blockIdx.x;          // t*256 + b, t in [0,120)
  int t = idx >> 8, b = idx & 255;
  int p = threadIdx.x;
  if (p < NPPAD) {
    float v = (p < NPOSE) ? poses[((size_t)b * 144 + t) * NPOSE + p] : 0.f;
    X[(size_t)idx * NPPAD + p] = (bf16)v;
  }
}

__device__ __forceinline__ float sigm(float x) { return 1.f / (1.f + __expf(-x)); }
__device__ __forceinline__ float tanh_(float x) {
  float e = __expf(2.f * x);
  return 1.f - 2.f / (e + 1.f);
}

template <bool DEEP>
__global__ __launch_bounds__(256, 1) void
k_main(const float* __restrict__ poses, const float* __restrict__ bfc,
       const bf16* __restrict__ Wcat, const bf16* __restrict__ Wfcb,
       bf16* __restrict__ X, bf16* __restrict__ H, int* __restrict__ bar,
       float* __restrict__ out) {
  // W staged to LDS once (r7/r9 layout, physical 128-wide chunks):
  // BldsH[p][r = gate*16 + j][k], 16B-group e stored at slot e ^ (r&15).
  // r14: LOGICAL chunks are 256-wide (physical pair 2c, 2c+1): 5 phases/step
  // instead of 9 -> fewer WAIT_VM boundaries, each phase's MFMA (~32) covers
  // the LLC load RTT.
  __shared__ bf16 BldsH[8 * 64 * 128];     // 128 KiB
  __shared__ bf16 BldsX[64 * LSTR];        // 21 KiB

  const int tid  = threadIdx.x;
  const int lane = tid & 63;
  const int wv   = tid >> 6;
  const int cl   = lane & 15;
  const int quad = lane >> 4;
  const int L    = blockIdx.x;
  const int jb = (L & 7) * 8 + ((L >> 3) & 7);   // XCD-aware j-block
  const int bb = L >> 6;                          // batch group
  const int b0 = bb * 64;
  const int j0 = jb * 16;
  const int mych = jb >> 3;                       // h-128chunk this WG produces
  const bool is_out = ((L & 7) == 7) && (((L >> 3) & 7) < 4);
  const int brow0 = bb * 64 + ((L >> 3) & 7) * 16;

  // ---- one-time B staging (plain loads; compiler-managed waits) ----
  for (int t = tid; t < 8 * 64 * 16; t += 256) {
    int c = t >> 10, rem = t & 1023, r = rem >> 4, xb = rem & 15;
    u32x4 v = *(const u32x4*)&Wcat[(size_t)((r >> 4) * NH + j0 + (r & 15)) * KTOT
                                   + c * 128 + xb * 8];
    *(u32x4*)&BldsH[(c * 64 + r) * 128 + ((xb ^ (r & 15)) << 3)] = v;
  }
  for (int it = 0; it < 5; ++it) {
    int u = tid + it * 256, r = u / 20, iu = u % 20;
    u32x4 v = *(const u32x4*)&Wcat[(size_t)((r >> 4) * NH + j0 + (r & 15)) * KTOT
                                   + 1024 + iu * 8];
    *(u32x4*)&BldsX[r * LSTR + iu * 8] = v;
  }
  __syncthreads();

  // ---- per-lane A addressing (direct-to-fragment; A never touches LDS) ----
  const int arow = b0 + wv * 16 + cl;                 // A row this lane owns
  const size_t aBase  = (size_t)arow * NH + quad * 8;
  const size_t axBase = (size_t)arow * NPPAD + quad * 8;

  u32x4 A0[8], A1[8], A2[8], AX[5];    // 3 rotating 256-wide sets + x
  f32x4 acc[4];
  float cst[4] = {0.f, 0.f, 0.f, 0.f};

// 256-wide logical chunk: 8 x 16B per lane, K offsets kk*32
#define ISSUE_AH(SET, HP, chn) do { \
    const bf16* ga_ = (HP) + aBase + (chn) * 256; \
    _Pragma("unroll") \
    for (int kk_ = 0; kk_ < 8; ++kk_) SET[kk_] = ld16sel(ga_ + kk_ * 32, DEEP); } while (0)
#define ISSUE_AX(sv) do { \
    const bf16* ga_ = X + (size_t)(sv) * NB * NPPAD + axBase; \
    if ((sv) < 120) { \
      AX[0] = g_ld16(ga_);        AX[1] = g_ld16(ga_ + 32); \
      AX[2] = g_ld16(ga_ + 64);   AX[3] = g_ld16(ga_ + 96); \
      AX[4] = g_ld16(ga_ + 128); \
    } else { \
      AX[0] = ld16sel(ga_, DEEP);       AX[1] = ld16sel(ga_ + 32, DEEP); \
      AX[2] = ld16sel(ga_ + 64, DEEP);  AX[3] = ld16sel(ga_ + 96, DEEP); \
      AX[4] = ld16sel(ga_ + 128, DEEP); \
    } } while (0)
// logical chunk c -> physical 128-chunks 2c (kk 0..3) and 2c+1 (kk 4..7)
#define MFMA_LDS(SET, c) do { \
    _Pragma("unroll") \
    for (int kk_ = 0; kk_ < 8; ++kk_) { \
      int p_ = (c) * 2 + (kk_ >> 2), ks_ = kk_ & 3; \
      bf16x8 af_ = __builtin_bit_cast(bf16x8, SET[kk_]); \
      _Pragma("unroll") \
      for (int gb = 0; gb < 4; ++gb) { \
        bf16x8 bw_ = *(const bf16x8*)&BldsH[(p_ * 64 + gb * 16 + cl) * 128 \
                                            + (((ks_ * 4 + quad) ^ cl) << 3)]; \
        acc[gb] = __builtin_amdgcn_mfma_f32_16x16x32_bf16(af_, bw_, acc[gb], 0, 0, 0); \
      } } } while (0)
#define MFMA_X() do { \
    _Pragma("unroll") \
    for (int ks = 0; ks < 5; ++ks) { \
      bf16x8 af_ = __builtin_bit_cast(bf16x8, AX[ks]); \
      _Pragma("unroll") \
      for (int gb = 0; gb < 4; ++gb) { \
        bf16x8 bw_ = *(const bf16x8*)&BldsX[(gb * 16 + cl) * LSTR + ks * 32 + quad * 8]; \
        acc[gb] = __builtin_amdgcn_mfma_f32_16x16x32_bf16(af_, bw_, acc[gb], 0, 0, 0); \
      } } } while (0)

  // ---- prologue: logical chunks 0,1 of step 0 (h(0)=zeros, slot 0) ----
  ISSUE_AH(A0, H, 0);
  ISSUE_AH(A1, H, 1);

  for (int s = 0; s < NSTEPS; ++s) {
    const bf16* Hr = H + (size_t)(DEEP ? s : (s & 1)) * (NB * NH);
    bf16* Hw = H + (size_t)(DEEP ? (s + 1) : ((s + 1) & 1)) * (NB * NH);
    #pragma unroll
    for (int gb = 0; gb < 4; ++gb) acc[gb] = f32x4{0, 0, 0, 0};

    // 5 phases: ledger 16 out at entry; issue 8 -> wait(16) retires a set.
    ISSUE_AH(A2, Hr, 2); WAIT_VM(16); MFMA_LDS(A0, 0);
    ISSUE_AH(A0, Hr, 3); WAIT_VM(16); MFMA_LDS(A1, 1);
    if (s >= 120) POLL(&bar[(32 + bb) * 32], 4 * (s - 119));   // decoder X gate
    ISSUE_AX(s);         WAIT_VM(18); MFMA_LDS(A2, 2);
                         WAIT_VM(10); MFMA_LDS(A0, 3);
                         WAIT_VM(0);  MFMA_X();

    // ---- activations + h-store (write-through) + ready signal ----
    #pragma unroll
    for (int r = 0; r < 4; ++r) {
      float gi = sigm(acc[0][r]);
      float gf = sigm(acc[1][r]);
      float gg = tanh_(acc[2][r]);
      float go = sigm(acc[3][r]);
      float cn = gf * cst[r] + gi * gg;
      cst[r] = cn;
      float h = go * tanh_(cn);
      bf16 hb = (bf16)h;
      llc_st2(&Hw[(size_t)(b0 + wv * 16 + quad * 4 + r) * NH + j0 + cl],
              (uint32_t)__builtin_bit_cast(uint16_t, hb));
    }
    WAIT_VM(0);                                     // h-tile acked at LLC
    __syncthreads();                                // all 4 waves stored
    if (tid == 0) atomicAdd(&bar[(bb * 8 + mych) * 32], 1);

    if (s >= 119 && is_out) {   // decoder: out = inp + h_new @ W_fc^T + b_fc
      const int k = s - 119;
      POLL_ALL8(8 * (s + 1));                       // full h(s+1) ready
      f32x4 oa[3] = {{0,0,0,0},{0,0,0,0},{0,0,0,0}};
      const bf16* hrow = Hw + (size_t)(brow0 + cl) * NH;
      for (int kb = 0; kb < 4; ++kb) {
        u32x4 hv[8];
        #pragma unroll
        for (int t = 0; t < 8; ++t)
          hv[t] = ld16sel(&hrow[(kb * 8 + t) * 32 + quad * 8], DEEP);
        WAIT_VM(0);
        #pragma unroll
        for (int t = 0; t < 8; ++t) {
          bf16x8 af = __builtin_bit_cast(bf16x8, hv[t]);
          #pragma unroll
          for (int i = 0; i < 3; ++i) {
            int ct = wv + i * 4;
            if (ct > 8) continue;
            bf16x8 bw = *(const bf16x8*)&Wfcb[(size_t)(ct * 16 + cl) * NH
                                              + (kb * 8 + t) * 32 + quad * 8];
            oa[i] = __builtin_amdgcn_mfma_f32_16x16x32_bf16(af, bw, oa[i], 0, 0, 0);
          }
        }
      }
      #pragma unroll
      for (int i = 0; i < 3; ++i) {
        int ct = wv + i * 4;
        if (ct > 8) continue;
        int p = ct * 16 + cl;
        if (p < NPOSE) {
          #pragma unroll
          for (int r = 0; r < 4; ++r) {
            int b = brow0 + quad * 4 + r;
            float inp = (k == 0) ? poses[((size_t)b * 144 + 119) * NPOSE + p]
                                 : out[((size_t)b * NDEC + (k - 1)) * NPOSE + p];
            float v = oa[i][r] + inp + bfc[p];       // additive chain kept fp32
            out[((size_t)b * NDEC + k) * NPOSE + p] = v;
            if (s + 1 < NSTEPS) {
              bf16 xb = (bf16)v;
              llc_st2(&X[((size_t)(s + 1) * NB + b) * NPPAD + p],
                      (uint32_t)__builtin_bit_cast(uint16_t, xb));
            }
          }
        }
      }
      if (s + 1 < NSTEPS) {
        WAIT_VM(0);                                 // X(s+1) acked at LLC
        __syncthreads();
        if (tid == 0) atomicAdd(&bar[(32 + bb) * 32], 1);
      }
    }

    // ---- tail: ballot readiness poll, then prefetch step s+1 chunks 0,1 ----
    if (s + 1 < NSTEPS) {
      POLL_ALL8(8 * (s + 1));
      ISSUE_AH(A0, Hw, 0);
      ISSUE_AH(A1, Hw, 1);
    }
  }
}

extern "C" void kernel_launch(void* const* d_in, const int* in_sizes, int n_in,
                              void* d_out, int out_size, void* d_ws, size_t ws_size,
                              hipStream_t stream) {
  const float* poses = (const float*)d_in[0];
  const float* Wih   = (const float*)d_in[1];
  const float* Whh   = (const float*)d_in[2];
  const float* Wfc   = (const float*)d_in[3];
  const float* bfc   = (const float*)d_in[4];

  const size_t need_deep = (size_t)H_OFF + H_BYTES144 + BAR_BYTES;
  const size_t need_min  = (size_t)H_OFF + H_BYTES2 + BAR_BYTES;
  if (ws_size < need_min) return;
  const bool deep = ws_size >= need_deep;
  const size_t hbytes = deep ? (size_t)H_BYTES144 : (size_t)H_BYTES2;

  char* ws = (char*)d_ws;
  bf16* Wcat = (bf16*)(ws + WCAT_OFF);
  bf16* Wfcb = (bf16*)(ws + WFC_OFF);
  bf16* X    = (bf16*)(ws + X_OFF);
  bf16* H    = (bf16*)(ws + H_OFF);
  int*  bar  = (int*)(ws + H_OFF + hbytes);

  if (deep) {
    k_zero<<<256, 256, 0, stream>>>((uint32_t*)(ws + H_OFF), (int)(NB * NH * 2 / 4));
    k_zero<<<32, 256, 0, stream>>>((uint32_t*)bar, BAR_BYTES / 4);
  } else {
    k_zero<<<256, 256, 0, stream>>>((uint32_t*)(ws + H_OFF),
                                    (int)((H_BYTES2 + BAR_BYTES) / 4));
  }
  k_zero<<<256, 256, 0, stream>>>((uint32_t*)(X + (size_t)120 * NB * NPPAD),
                                  (int)(23l * NB * NPPAD * 2 / 4));
  k_wcat<<<4096, 256, 0, stream>>>(Whh, Wih, Wcat);
  k_wfc<<<144, 256, 0, stream>>>(Wfc, Wfcb);
  k_x<<<120 * 256, 256, 0, stream>>>(poses, X);
  if (deep)
    k_main<true><<<NWG, 256, 0, stream>>>(poses, bfc, Wcat, Wfcb, X, H, bar,
                                          (float*)d_out);
  else
    k_main<false><<<NWG, 256, 0, stream>>>(poses, bfc, Wcat, Wfcb, X, H, bar,
                                           (float*)d_out);
}

// Round 15
// 1558.071 us; speedup vs baseline: 1.4793x; 1.0710x over previous
//
#include <hip/hip_runtime.h>
#include <stdint.h>

#define NB 256          // batch
#define NH 1024         // hidden
#define NPOSE 135
#define NPPAD 160       // pose padded to 160
#define NSTEPS 143      // 119 encoder + 24 decoder cell steps
#define NDEC 24
#define KTOT 1184       // 1024 (h) + 160 (x padded)
#define LSTR 168        // LDS row stride for x-B chunk
#define NWG 256

typedef __bf16 bf16;
typedef __attribute__((ext_vector_type(8))) __bf16 bf16x8;
typedef __attribute__((ext_vector_type(4))) float f32x4;
typedef __attribute__((ext_vector_type(4))) uint32_t u32x4;

// ---- ws layout (bytes) ----
#define WCAT_OFF 0
#define WCAT_BYTES (4096l * KTOT * 2)
#define WFC_OFF  (WCAT_OFF + WCAT_BYTES)
#define WFC_BYTES (144l * 1024 * 2)
#define X_OFF    (WFC_OFF + WFC_BYTES)
#define X_BYTES  (143l * NB * NPPAD * 2)
#define H_OFF    (X_OFF + X_BYTES)
#define H_BYTES2    (2l * NB * NH * 2)     // fallback: ping-pong
#define H_BYTES144  (144l * NB * NH * 2)   // deep: slot per step -> cacheable
#define BAR_BYTES 16384
// bar ints, one counter per 128B line:
//   cnt[bb][ch] at bar[(bb*8+ch)*32]  (h-chunk ready; 8 producers, +8/step)
//   xcnt[bb]    at bar[(32+bb)*32]    (decoder X ready; +4/out-step)

__device__ __forceinline__ u32x4 llc_ld16(const void* p) {
  u32x4 v;
  asm volatile("global_load_dwordx4 %0, %1, off sc0 sc1"
               : "=v"(v) : "v"(p) : "memory");
  return v;
}
__device__ __forceinline__ uint32_t llc_ld4(const void* p) {   // pipelined flag load
  uint32_t v;
  asm volatile("global_load_dword %0, %1, off sc0 sc1"
               : "=v"(v) : "v"(p) : "memory");
  return v;
}
__device__ __forceinline__ u32x4 g_ld16(const void* p) {   // cached
  u32x4 v;
  asm volatile("global_load_dwordx4 %0, %1, off"
               : "=v"(v) : "v"(p) : "memory");
  return v;
}
__device__ __forceinline__ u32x4 ld16sel(const void* p, bool cached) {
  return cached ? g_ld16(p) : llc_ld16(p);
}
__device__ __forceinline__ void llc_st2(void* p, uint32_t v) {
  asm volatile("global_store_short %0, %1, off sc0 sc1"
               :: "v"(p), "v"(v) : "memory");
}
#define WAIT_VM(n) do { \
    asm volatile("s_waitcnt vmcnt(" #n ")" ::: "memory"); \
    __builtin_amdgcn_sched_barrier(0); } while (0)

// Blocking polls force vmcnt(0) (newest-load rule): allowed only at tail /
// decoder / slow path. Fast-path chunk gating uses PIPELINED flag loads that
// retire through the normal phase WAIT_VM ledger (zero extra stalls).
#define POLL(ptr, tgt) do { \
    while (__hip_atomic_load((ptr), __ATOMIC_RELAXED, __HIP_MEMORY_SCOPE_AGENT) < (tgt)) \
      __builtin_amdgcn_s_sleep(1); \
  } while (0)
#define POLL_ALL8(tgt) do { \
    for (;;) { \
      int v_ = __hip_atomic_load(&bar[(bb * 8 + (lane & 7)) * 32], \
                                 __ATOMIC_RELAXED, __HIP_MEMORY_SCOPE_AGENT); \
      if (__all(v_ >= (tgt))) break; \
      __builtin_amdgcn_s_sleep(1); \
    } } while (0)
#define POLL01(tgt) do { \
    for (;;) { \
      int v_ = __hip_atomic_load(&bar[(bb * 8 + (lane & 1)) * 32], \
                                 __ATOMIC_RELAXED, __HIP_MEMORY_SCOPE_AGENT); \
      if (__all(v_ >= (tgt))) break; \
      __builtin_amdgcn_s_sleep(1); \
    } } while (0)
// fast-path check of a pipelined flag value (uniform across lanes); slow path
// re-loads with full drain (rare: producer genuinely late). Under-running the
// ledger after a drain is safe (WAIT_VM(n) is a no-op when fewer outstanding).
#define CHK(fv, ch, tgt) do { \
    while ((int)(fv) < (tgt)) { \
      __builtin_amdgcn_s_sleep(1); \
      fv = llc_ld4(&bar[(bb * 8 + (ch)) * 32]); \
      WAIT_VM(0); \
    } } while (0)

__global__ void k_zero(uint32_t* p, int n) {
  int i = blockIdx.x * blockDim.x + threadIdx.x;
  int st = gridDim.x * blockDim.x;
  for (; i < n; i += st) p[i] = 0u;
}

__global__ void k_wcat(const float* __restrict__ Whh, const float* __restrict__ Wih,
                       bf16* __restrict__ W) {
  int n = blockIdx.x;
  for (int kk = threadIdx.x; kk < KTOT; kk += blockDim.x) {
    float v = 0.f;
    if (kk < NH) v = Whh[(size_t)n * NH + kk];
    else if (kk - NH < NPOSE) v = Wih[(size_t)n * NPOSE + (kk - NH)];
    W[(size_t)n * KTOT + kk] = (bf16)v;
  }
}

__global__ void k_wfc(const float* __restrict__ Wfc, bf16* __restrict__ W) {
  int p = blockIdx.x;
  for (int kk = threadIdx.x; kk < NH; kk += blockDim.x) {
    float v = (p < NPOSE) ? Wfc[(size_t)p * NH + kk] : 0.f;
    W[(size_t)p * NH + kk] = (bf16)v;
  }
}

__global__ void k_x(const float* __restrict__ poses, bf16* __restrict__ X) {
  int idx = blockIdx.x;          // t*256 + b, t in [0,120)
  int t = idx >> 8, b = idx & 255;
  int p = threadIdx.x;
  if (p < NPPAD) {
    float v = (p < NPOSE) ? poses[((size_t)b * 144 + t) * NPOSE + p] : 0.f;
    X[(size_t)idx * NPPAD + p] = (bf16)v;
  }
}

__device__ __forceinline__ float sigm(float x) { return 1.f / (1.f + __expf(-x)); }
__device__ __forceinline__ float tanh_(float x) {
  float e = __expf(2.f * x);
  return 1.f - 2.f / (e + 1.f);
}

template <bool DEEP>
__global__ __launch_bounds__(256, 1) void
k_main(const float* __restrict__ poses, const float* __restrict__ bfc,
       const bf16* __restrict__ Wcat, const bf16* __restrict__ Wfcb,
       bf16* __restrict__ X, bf16* __restrict__ H, int* __restrict__ bar,
       float* __restrict__ out) {
  // W staged to LDS once (r7/r9 layout):
  // BldsH[c][r = gate*16 + j][k], 16B-group e stored at slot e ^ (r&15).
  __shared__ bf16 BldsH[8 * 64 * 128];     // 128 KiB
  __shared__ bf16 BldsX[64 * LSTR];        // 21 KiB

  const int tid  = threadIdx.x;
  const int lane = tid & 63;
  const int wv   = tid >> 6;
  const int cl   = lane & 15;
  const int quad = lane >> 4;
  const int L    = blockIdx.x;
  const int jb = (L & 7) * 8 + ((L >> 3) & 7);   // XCD-aware j-block
  const int bb = L >> 6;                          // batch group
  const int b0 = bb * 64;
  const int j0 = jb * 16;
  const int mych = jb >> 3;                       // h-chunk this WG produces
  const bool is_out = ((L & 7) == 7) && (((L >> 3) & 7) < 4);
  const int brow0 = bb * 64 + ((L >> 3) & 7) * 16;

  // ---- one-time B staging (plain loads; compiler-managed waits) ----
  for (int t = tid; t < 8 * 64 * 16; t += 256) {
    int c = t >> 10, rem = t & 1023, r = rem >> 4, xb = rem & 15;
    u32x4 v = *(const u32x4*)&Wcat[(size_t)((r >> 4) * NH + j0 + (r & 15)) * KTOT
                                   + c * 128 + xb * 8];
    *(u32x4*)&BldsH[(c * 64 + r) * 128 + ((xb ^ (r & 15)) << 3)] = v;
  }
  for (int it = 0; it < 5; ++it) {
    int u = tid + it * 256, r = u / 20, iu = u % 20;
    u32x4 v = *(const u32x4*)&Wcat[(size_t)((r >> 4) * NH + j0 + (r & 15)) * KTOT
                                   + 1024 + iu * 8];
    *(u32x4*)&BldsX[r * LSTR + iu * 8] = v;
  }
  __syncthreads();

  // ---- per-lane A addressing (direct-to-fragment; A never touches LDS) ----
  const int arow = b0 + wv * 16 + cl;                 // A row this lane owns
  const size_t aBase  = (size_t)arow * NH + quad * 8;
  const size_t axBase = (size_t)arow * NPPAD + quad * 8;

  u32x4 A0[4], A1[4], A2[4], AX[5];
  uint32_t f2 = 0, f3 = 0, f4 = 0, f5 = 0, f6 = 0, f7 = 0;
  f32x4 acc[4];
  float cst[4] = {0.f, 0.f, 0.f, 0.f};

#define FLAGP(ch) (&bar[(bb * 8 + (ch)) * 32])
#define ISSUE_AH(SET, HP, chn) do { \
    const bf16* ga_ = (HP) + aBase + (chn) * 128; \
    SET[0] = ld16sel(ga_, DEEP);      SET[1] = ld16sel(ga_ + 32, DEEP); \
    SET[2] = ld16sel(ga_ + 64, DEEP); SET[3] = ld16sel(ga_ + 96, DEEP); } while (0)
#define ISSUE_AX(sv) do { \
    const bf16* ga_ = X + (size_t)(sv) * NB * NPPAD + axBase; \
    if ((sv) < 120) { \
      AX[0] = g_ld16(ga_);        AX[1] = g_ld16(ga_ + 32); \
      AX[2] = g_ld16(ga_ + 64);   AX[3] = g_ld16(ga_ + 96); \
      AX[4] = g_ld16(ga_ + 128); \
    } else { \
      AX[0] = ld16sel(ga_, DEEP);       AX[1] = ld16sel(ga_ + 32, DEEP); \
      AX[2] = ld16sel(ga_ + 64, DEEP);  AX[3] = ld16sel(ga_ + 96, DEEP); \
      AX[4] = ld16sel(ga_ + 128, DEEP); \
    } } while (0)
#define MFMA_LDS(SET, c) do { \
    _Pragma("unroll") \
    for (int ks = 0; ks < 4; ++ks) { \
      bf16x8 af_ = __builtin_bit_cast(bf16x8, SET[ks]); \
      _Pragma("unroll") \
      for (int gb = 0; gb < 4; ++gb) { \
        bf16x8 bw_ = *(const bf16x8*)&BldsH[((c) * 64 + gb * 16 + cl) * 128 \
                                            + (((ks * 4 + quad) ^ cl) << 3)]; \
        acc[gb] = __builtin_amdgcn_mfma_f32_16x16x32_bf16(af_, bw_, acc[gb], 0, 0, 0); \
      } } } while (0)
#define MFMA_X() do { \
    _Pragma("unroll") \
    for (int ks = 0; ks < 5; ++ks) { \
      bf16x8 af_ = __builtin_bit_cast(bf16x8, AX[ks]); \
      _Pragma("unroll") \
      for (int gb = 0; gb < 4; ++gb) { \
        bf16x8 bw_ = *(const bf16x8*)&BldsX[(gb * 16 + cl) * LSTR + ks * 32 + quad * 8]; \
        acc[gb] = __builtin_amdgcn_mfma_f32_16x16x32_bf16(af_, bw_, acc[gb], 0, 0, 0); \
      } } } while (0)

  // ---- prologue: step 0 (h(0)=zeros, flags 0 -> targets 0 pass trivially) ----
  // FIFO issue order must be A0,F2,A1,F3 (ledger contract).
  ISSUE_AH(A0, H, 0);  f2 = llc_ld4(FLAGP(2));
  ISSUE_AH(A1, H, 1);  f3 = llc_ld4(FLAGP(3));

  for (int s = 0; s < NSTEPS; ++s) {
    const bf16* Hr = H + (size_t)(DEEP ? s : (s & 1)) * (NB * NH);
    bf16* Hw = H + (size_t)(DEEP ? (s + 1) : ((s + 1) & 1)) * (NB * NH);
    #pragma unroll
    for (int gb = 0; gb < 4; ++gb) acc[gb] = f32x4{0, 0, 0, 0};
    const int tgt = 8 * s;    // h(s) chunk-ready target

    // Ledger (FIFO): entry [A0(4),F2,A1(4),F3] = 10.
    // Each phase: WAIT retires its data + the flag checked this phase.
    WAIT_VM(5); CHK(f2, 2, tgt); ISSUE_AH(A2, Hr, 2); f4 = llc_ld4(FLAGP(4)); MFMA_LDS(A0, 0);
    WAIT_VM(5); CHK(f3, 3, tgt); ISSUE_AH(A0, Hr, 3); f5 = llc_ld4(FLAGP(5)); MFMA_LDS(A1, 1);
    WAIT_VM(5); CHK(f4, 4, tgt); ISSUE_AH(A1, Hr, 4); f6 = llc_ld4(FLAGP(6)); MFMA_LDS(A2, 2);
    WAIT_VM(5); CHK(f5, 5, tgt); ISSUE_AH(A2, Hr, 5); f7 = llc_ld4(FLAGP(7)); MFMA_LDS(A0, 3);
    WAIT_VM(5); CHK(f6, 6, tgt); ISSUE_AH(A0, Hr, 6);                         MFMA_LDS(A1, 4);
    WAIT_VM(4); CHK(f7, 7, tgt); ISSUE_AH(A1, Hr, 7);                         MFMA_LDS(A2, 5);
    WAIT_VM(4);
    if (s >= 120) POLL(&bar[(32 + bb) * 32], 4 * (s - 119));   // decoder X gate
    ISSUE_AX(s);                                               MFMA_LDS(A0, 6);
    WAIT_VM(5);                                                MFMA_LDS(A1, 7);
    WAIT_VM(0);                                                MFMA_X();

    // ---- activations + h-store (write-through) + ready signal ----
    #pragma unroll
    for (int r = 0; r < 4; ++r) {
      float gi = sigm(acc[0][r]);
      float gf = sigm(acc[1][r]);
      float gg = tanh_(acc[2][r]);
      float go = sigm(acc[3][r]);
      float cn = gf * cst[r] + gi * gg;
      cst[r] = cn;
      float h = go * tanh_(cn);
      bf16 hb = (bf16)h;
      llc_st2(&Hw[(size_t)(b0 + wv * 16 + quad * 4 + r) * NH + j0 + cl],
              (uint32_t)__builtin_bit_cast(uint16_t, hb));
    }
    WAIT_VM(0);                                     // h-tile acked at LLC
    __syncthreads();                                // all 4 waves stored
    if (tid == 0) atomicAdd(&bar[(bb * 8 + mych) * 32], 1);

    if (s >= 119 && is_out) {   // decoder: out = inp + h_new @ W_fc^T + b_fc
      const int k = s - 119;
      POLL_ALL8(8 * (s + 1));                       // full h(s+1) ready
      f32x4 oa[3] = {{0,0,0,0},{0,0,0,0},{0,0,0,0}};
      const bf16* hrow = Hw + (size_t)(brow0 + cl) * NH;
      for (int kb = 0; kb < 4; ++kb) {
        u32x4 hv[8];
        #pragma unroll
        for (int t = 0; t < 8; ++t)
          hv[t] = ld16sel(&hrow[(kb * 8 + t) * 32 + quad * 8], DEEP);
        WAIT_VM(0);
        #pragma unroll
        for (int t = 0; t < 8; ++t) {
          bf16x8 af = __builtin_bit_cast(bf16x8, hv[t]);
          #pragma unroll
          for (int i = 0; i < 3; ++i) {
            int ct = wv + i * 4;
            if (ct > 8) continue;
            bf16x8 bw = *(const bf16x8*)&Wfcb[(size_t)(ct * 16 + cl) * NH
                                              + (kb * 8 + t) * 32 + quad * 8];
            oa[i] = __builtin_amdgcn_mfma_f32_16x16x32_bf16(af, bw, oa[i], 0, 0, 0);
          }
        }
      }
      #pragma unroll
      for (int i = 0; i < 3; ++i) {
        int ct = wv + i * 4;
        if (ct > 8) continue;
        int p = ct * 16 + cl;
        if (p < NPOSE) {
          #pragma unroll
          for (int r = 0; r < 4; ++r) {
            int b = brow0 + quad * 4 + r;
            float inp = (k == 0) ? poses[((size_t)b * 144 + 119) * NPOSE + p]
                                 : out[((size_t)b * NDEC + (k - 1)) * NPOSE + p];
            float v = oa[i][r] + inp + bfc[p];       // additive chain kept fp32
            out[((size_t)b * NDEC + k) * NPOSE + p] = v;
            if (s + 1 < NSTEPS) {
              bf16 xb = (bf16)v;
              llc_st2(&X[((size_t)(s + 1) * NB + b) * NPPAD + p],
                      (uint32_t)__builtin_bit_cast(uint16_t, xb));
            }
          }
        }
      }
      if (s + 1 < NSTEPS) {
        WAIT_VM(0);                                 // X(s+1) acked at LLC
        __syncthreads();
        if (tid == 0) atomicAdd(&bar[(32 + bb) * 32], 1);
      }
    }

    // ---- tail: gate chunks 0,1 only (DEEP: write-once slots -> no WAR);
    //      fallback keeps the all-8 gate (ping-pong WAR safety, as r9). ----
    if (s + 1 < NSTEPS) {
      if constexpr (DEEP) { POLL01(8 * (s + 1)); }
      else                { POLL_ALL8(8 * (s + 1)); }
      ISSUE_AH(A0, Hw, 0);  f2 = llc_ld4(FLAGP(2));
      ISSUE_AH(A1, Hw, 1);  f3 = llc_ld4(FLAGP(3));
    }
  }
}

extern "C" void kernel_launch(void* const* d_in, const int* in_sizes, int n_in,
                              void* d_out, int out_size, void* d_ws, size_t ws_size,
                              hipStream_t stream) {
  const float* poses = (const float*)d_in[0];
  const float* Wih   = (const float*)d_in[1];
  const float* Whh   = (const float*)d_in[2];
  const float* Wfc   = (const float*)d_in[3];
  const float* bfc   = (const float*)d_in[4];

  const size_t need_deep = (size_t)H_OFF + H_BYTES144 + BAR_BYTES;
  const size_t need_min  = (size_t)H_OFF + H_BYTES2 + BAR_BYTES;
  if (ws_size < need_min) return;
  const bool deep = ws_size >= need_deep;
  const size_t hbytes = deep ? (size_t)H_BYTES144 : (size_t)H_BYTES2;

  char* ws = (char*)d_ws;
  bf16* Wcat = (bf16*)(ws + WCAT_OFF);
  bf16* Wfcb = (bf16*)(ws + WFC_OFF);
  bf16* X    = (bf16*)(ws + X_OFF);
  bf16* H    = (bf16*)(ws + H_OFF);
  int*  bar  = (int*)(ws + H_OFF + hbytes);

  if (deep) {
    k_zero<<<256, 256, 0, stream>>>((uint32_t*)(ws + H_OFF), (int)(NB * NH * 2 / 4));
    k_zero<<<32, 256, 0, stream>>>((uint32_t*)bar, BAR_BYTES / 4);
  } else {
    k_zero<<<256, 256, 0, stream>>>((uint32_t*)(ws + H_OFF),
                                    (int)((H_BYTES2 + BAR_BYTES) / 4));
  }
  k_zero<<<256, 256, 0, stream>>>((uint32_t*)(X + (size_t)120 * NB * NPPAD),
                                  (int)(23l * NB * NPPAD * 2 / 4));
  k_wcat<<<4096, 256, 0, stream>>>(Whh, Wih, Wcat);
  k_wfc<<<144, 256, 0, stream>>>(Wfc, Wfcb);
  k_x<<<120 * 256, 256, 0, stream>>>(poses, X);
  if (deep)
    k_main<true><<<NWG, 256, 0, stream>>>(poses, bfc, Wcat, Wfcb, X, H, bar,
                                          (float*)d_out);
  else
    k_main<false><<<NWG, 256, 0, stream>>>(poses, bfc, Wcat, Wfcb, X, H, bar,
                                           (float*)d_out);
}